// Round 1
// baseline (286.674 us; speedup 1.0000x reference)
//
#include <hip/hip_runtime.h>
#include <hip/hip_bf16.h>

typedef __attribute__((ext_vector_type(8))) short s16x8;
typedef __attribute__((ext_vector_type(4))) float f32x4;

#define GLOAD_LDS16(gsrc, ldst) \
  __builtin_amdgcn_global_load_lds((const __attribute__((address_space(1))) void*)(gsrc), \
      (__attribute__((address_space(3))) void*)(ldst), 16, 0, 0)

// ---------------------------------------------------------------------------
// f32 -> bf16 convert (vectorized, n divisible by 1024)
// ---------------------------------------------------------------------------
__global__ __launch_bounds__(256) void cvt_bf16(const float* __restrict__ in,
                                                __hip_bfloat16* __restrict__ out, long n) {
  long i = ((long)blockIdx.x * 256 + threadIdx.x) * 4;
  if (i + 3 >= n) return;
  float4 v = *(const float4*)(in + i);
  __hip_bfloat16 tmp[4] = {__float2bfloat16(v.x), __float2bfloat16(v.y),
                           __float2bfloat16(v.z), __float2bfloat16(v.w)};
  *(ushort4*)((unsigned short*)out + i) = *(const ushort4*)tmp;
}

// ---------------------------------------------------------------------------
// merge + transpose:  Out[b][n][k] = bf16( W[k][n] + sum_e coeff[b][e]*T[e][k][n] )
// NB=1,nE=0 doubles as a plain transpose-convert for router weights.
// tile 64x64, 256 threads, coalesced reads along n, coalesced writes along k.
// ---------------------------------------------------------------------------
template<int NB>
__global__ __launch_bounds__(256) void merge_transpose(
    const float* __restrict__ Wb, const float* __restrict__ T,
    const float* __restrict__ coeff, __hip_bfloat16* __restrict__ Out,
    int K, int N, int nE) {
  int ntn = N >> 6;
  int k0 = (blockIdx.x / ntn) << 6;
  int n0 = (blockIdx.x % ntn) << 6;
  int t = threadIdx.x;
  long KN = (long)K * N;

  float accb[NB][16];
#pragma unroll
  for (int i = 0; i < 16; ++i) {
    int e = i * 256 + t; int kk = e >> 6, nn = e & 63;
    float bv = Wb[(long)(k0 + kk) * N + n0 + nn];
#pragma unroll
    for (int b2 = 0; b2 < NB; ++b2) accb[b2][i] = bv;
  }
  for (int ex = 0; ex < nE; ++ex) {
    float c[NB];
#pragma unroll
    for (int b2 = 0; b2 < NB; ++b2) c[b2] = coeff[b2 * 8 + ex];
#pragma unroll
    for (int i = 0; i < 16; ++i) {
      int e = i * 256 + t; int kk = e >> 6, nn = e & 63;
      float tv = T[(long)ex * KN + (long)(k0 + kk) * N + n0 + nn];
#pragma unroll
      for (int b2 = 0; b2 < NB; ++b2) accb[b2][i] += c[b2] * tv;
    }
  }
  __shared__ __hip_bfloat16 lds[64 * 66];
  for (int b2 = 0; b2 < NB; ++b2) {
    __syncthreads();
#pragma unroll
    for (int i = 0; i < 16; ++i) {
      int e = i * 256 + t; int kk = e >> 6, nn = e & 63;
      lds[kk * 66 + nn] = __float2bfloat16(accb[b2][i]);
    }
    __syncthreads();
#pragma unroll
    for (int i = 0; i < 16; ++i) {
      int o = i * 256 + t; int n2 = o >> 6, k2 = o & 63;
      Out[(long)b2 * KN + (long)(n0 + n2) * K + k0 + k2] = lds[k2 * 66 + n2];
    }
  }
}

// ---------------------------------------------------------------------------
// merged bias: out[b][i] = base[i] + sum_e coeff[b][e]*T[e][i]
// ---------------------------------------------------------------------------
__global__ __launch_bounds__(256) void merge_bias(const float* __restrict__ base,
                                                  const float* __restrict__ T,
                                                  const float* __restrict__ coeff,
                                                  float* __restrict__ out, int n) {
  int b = blockIdx.y;
  int i = blockIdx.x * 256 + threadIdx.x;
  if (i >= n) return;
  float v = base[i];
#pragma unroll
  for (int e = 0; e < 8; ++e) v += coeff[b * 8 + e] * T[(long)e * n + i];
  out[(long)b * n + i] = v;
}

// ---------------------------------------------------------------------------
// GEMM: C = act(A @ B + bias).  A: [M,K] bf16 row-major.  BT: [N,K] bf16 row-major
// (i.e. B stored N-major).  128x128 tile, BK=64, 4 waves, 16x16x32 bf16 MFMA,
// global_load_lds width 16, XOR-swizzled LDS (linear dest + pre-swizzled source).
// M%128==0, N%128==0, K%64==0 assumed (true for all shapes here).
// ACT: 0=none 1=relu 2=gelu(exact).  OUTBF: write bf16 else f32.
// ---------------------------------------------------------------------------
template<int ACT, bool OUTBF>
__global__ __launch_bounds__(256, 2) void gemm_bt(
    const __hip_bfloat16* __restrict__ A, const __hip_bfloat16* __restrict__ BT,
    const float* __restrict__ bias, void* __restrict__ Out,
    int M, int N, int K, long sA, long sB, long sBias, long sOut) {
  int b = blockIdx.y;
  const __hip_bfloat16* Ab = A + (long)b * sA;
  const __hip_bfloat16* Bb = BT + (long)b * sB;
  const float* biasb = bias + (long)b * sBias;

  int ntn = N >> 7;
  int m0 = (blockIdx.x / ntn) << 7;
  int n0 = (blockIdx.x % ntn) << 7;

  __shared__ __align__(16) __hip_bfloat16 As[128 * 64];
  __shared__ __align__(16) __hip_bfloat16 Bs[128 * 64];

  int t = threadIdx.x;
  int lane = t & 63;
  int wid = t >> 6;
  int wm = wid >> 1, wn = wid & 1;
  int lr = lane & 15, kg = lane >> 4;

  f32x4 acc[4][4] = {};

  for (int kt = 0; kt < K; kt += 64) {
#pragma unroll
    for (int is = 0; is < 4; ++is) {
      int ci = is * 256 + t;
      int row = ci >> 3, cpos = ci & 7;
      int csrc = cpos ^ (row & 7);
      GLOAD_LDS16(Ab + (long)(m0 + row) * K + kt + csrc * 8, &As[ci * 8]);
      GLOAD_LDS16(Bb + (long)(n0 + row) * K + kt + csrc * 8, &Bs[ci * 8]);
    }
    __syncthreads();
#pragma unroll
    for (int ks = 0; ks < 2; ++ks) {
      s16x8 af[4], bfr[4];
#pragma unroll
      for (int m = 0; m < 4; ++m) {
        int row = wm * 64 + m * 16 + lr;
        int c = (ks * 4 + kg) ^ (row & 7);
        af[m] = *(const s16x8*)&As[row * 64 + c * 8];
      }
#pragma unroll
      for (int n = 0; n < 4; ++n) {
        int row = wn * 64 + n * 16 + lr;
        int c = (ks * 4 + kg) ^ (row & 7);
        bfr[n] = *(const s16x8*)&Bs[row * 64 + c * 8];
      }
#pragma unroll
      for (int m = 0; m < 4; ++m)
#pragma unroll
        for (int n = 0; n < 4; ++n)
          acc[m][n] = __builtin_amdgcn_mfma_f32_16x16x32_bf16(af[m], bfr[n], acc[m][n], 0, 0, 0);
    }
    __syncthreads();
  }

#pragma unroll
  for (int n = 0; n < 4; ++n) {
    int col = n0 + wn * 64 + n * 16 + lr;
    float bv = biasb[col];
#pragma unroll
    for (int m = 0; m < 4; ++m) {
      int row0 = m0 + wm * 64 + m * 16 + kg * 4;
#pragma unroll
      for (int j = 0; j < 4; ++j) {
        float v = acc[m][n][j] + bv;
        if (ACT == 1) v = fmaxf(v, 0.f);
        else if (ACT == 2) v = 0.5f * v * (1.f + erff(v * 0.70710678118f));
        long off = (long)b * sOut + (long)(row0 + j) * N + col;
        if (OUTBF) ((__hip_bfloat16*)Out)[off] = __float2bfloat16(v);
        else ((float*)Out)[off] = v;
      }
    }
  }
}

// ---------------------------------------------------------------------------
// router logits + per-row softmax.  One block per token row (4096 rows).
// ---------------------------------------------------------------------------
__global__ __launch_bounds__(256) void router_logits(
    const __hip_bfloat16* __restrict__ Hg2, const float* __restrict__ Wgo,
    const float* __restrict__ bgo, float* __restrict__ probs) {
  int r = blockIdx.x;
  int t = threadIdx.x;
  float acc[8] = {};
#pragma unroll
  for (int j = 0; j < 4; ++j) {
    int k = j * 256 + t;
    float h = __bfloat162float(Hg2[(long)r * 1024 + k]);
    const float4* wp = (const float4*)&Wgo[k * 8];
    float4 w0 = wp[0], w1 = wp[1];
    acc[0] += h * w0.x; acc[1] += h * w0.y; acc[2] += h * w0.z; acc[3] += h * w0.w;
    acc[4] += h * w1.x; acc[5] += h * w1.y; acc[6] += h * w1.z; acc[7] += h * w1.w;
  }
#pragma unroll
  for (int off = 32; off >= 1; off >>= 1)
#pragma unroll
    for (int e = 0; e < 8; ++e) acc[e] += __shfl_down(acc[e], off);
  __shared__ float lds[4][8];
  int wid = t >> 6, lane = t & 63;
  if (lane == 0)
#pragma unroll
    for (int e = 0; e < 8; ++e) lds[wid][e] = acc[e];
  __syncthreads();
  if (t == 0) {
    float lg[8];
#pragma unroll
    for (int e = 0; e < 8; ++e) lg[e] = lds[0][e] + lds[1][e] + lds[2][e] + lds[3][e] + bgo[e];
    float mx = lg[0];
#pragma unroll
    for (int e = 1; e < 8; ++e) mx = fmaxf(mx, lg[e]);
    float s = 0.f;
#pragma unroll
    for (int e = 0; e < 8; ++e) { lg[e] = __expf(lg[e] - mx); s += lg[e]; }
    float inv = 1.f / s;
#pragma unroll
    for (int e = 0; e < 8; ++e) probs[(long)r * 8 + e] = lg[e] * inv;
  }
}

// ---------------------------------------------------------------------------
// mean over seq + coeff = gate + ohe.  One block per batch sample.
// ---------------------------------------------------------------------------
__global__ __launch_bounds__(256) void router_mean(
    const float* __restrict__ probs, const float* __restrict__ ohe,
    float* __restrict__ gate_out, float* __restrict__ coeff) {
  int b = blockIdx.x;
  int t = threadIdx.x;
  int e = t & 7, sg = t >> 3;
  float s = 0.f;
#pragma unroll
  for (int j = 0; j < 16; ++j)
    s += probs[((long)b * 512 + sg + j * 32) * 8 + e];
  __shared__ float lds[256];
  lds[t] = s;
  __syncthreads();
  if (t < 8) {
    float tot = 0.f;
#pragma unroll
    for (int g = 0; g < 32; ++g) tot += lds[g * 8 + t];
    float gw = tot / 512.f;
    gate_out[b * 8 + t] = gw;
    coeff[b * 8 + t] = gw + ohe[b * 8 + t];
  }
}

// ---------------------------------------------------------------------------
extern "C" void kernel_launch(void* const* d_in, const int* in_sizes, int n_in,
                              void* d_out, int out_size, void* d_ws, size_t ws_size,
                              hipStream_t stream) {
  const float* x    = (const float*)d_in[0];
  const float* ohe  = (const float*)d_in[1];
  const float* W1   = (const float*)d_in[2];
  const float* b1   = (const float*)d_in[3];
  const float* W2   = (const float*)d_in[4];
  const float* b2   = (const float*)d_in[5];
  const float* T_W1 = (const float*)d_in[6];
  const float* T_b1 = (const float*)d_in[7];
  const float* T_W2 = (const float*)d_in[8];
  const float* T_b2 = (const float*)d_in[9];
  const float* Wg1  = (const float*)d_in[10];
  const float* bg1  = (const float*)d_in[11];
  const float* Wg2  = (const float*)d_in[12];
  const float* bg2  = (const float*)d_in[13];
  const float* Wgo  = (const float*)d_in[14];
  const float* bgo  = (const float*)d_in[15];
  float* out = (float*)d_out;                 // [8,512,1024] then gate [8,8]
  float* gate_out = out + (long)8 * 512 * 1024;

  char* w = (char*)d_ws;
  __hip_bfloat16* xb   = (__hip_bfloat16*)(w);
  __hip_bfloat16* Wg1T = (__hip_bfloat16*)(w + 8388608);
  __hip_bfloat16* Wg2T = (__hip_bfloat16*)(w + 10485760);
  __hip_bfloat16* Hg1  = (__hip_bfloat16*)(w + 12582912);
  __hip_bfloat16* Hg2  = (__hip_bfloat16*)(w + 20971520);
  float*          probs= (float*)(w + 29360128);
  float*          coeff= (float*)(w + 29491200);
  float*          b1b  = (float*)(w + 29492224);
  float*          b2b  = (float*)(w + 29623296);
  __hip_bfloat16* hmid = (__hip_bfloat16*)(w + 29656064);
  __hip_bfloat16* Wb   = (__hip_bfloat16*)(w + 63210496);   // 67 MB, reused W1bT then W2bT

  // 1. x -> bf16
  cvt_bf16<<<4096, 256, 0, stream>>>(x, xb, (long)8 * 512 * 1024);
  // 2. router weight transpose-converts
  merge_transpose<1><<<16 * 16, 256, 0, stream>>>(Wg1, nullptr, nullptr, Wg1T, 1024, 1024, 0);
  merge_transpose<1><<<16 * 16, 256, 0, stream>>>(Wg2, nullptr, nullptr, Wg2T, 1024, 1024, 0);
  // 3. router GEMMs (M=4096,N=1024,K=1024), relu
  gemm_bt<1, true><<<dim3(32 * 8, 1), 256, 0, stream>>>(xb, Wg1T, bg1, Hg1,
      4096, 1024, 1024, 0, 0, 0, 0);
  gemm_bt<1, true><<<dim3(32 * 8, 1), 256, 0, stream>>>(Hg1, Wg2T, bg2, Hg2,
      4096, 1024, 1024, 0, 0, 0, 0);
  // 4. logits + softmax, then mean + coeff
  router_logits<<<4096, 256, 0, stream>>>(Hg2, Wgo, bgo, probs);
  router_mean<<<8, 256, 0, stream>>>(probs, ohe, gate_out, coeff);
  // 5. merged biases
  merge_bias<<<dim3(16, 8), 256, 0, stream>>>(b1, T_b1, coeff, b1b, 4096);
  merge_bias<<<dim3(4, 8), 256, 0, stream>>>(b2, T_b2, coeff, b2b, 1024);
  // 6. W1bT (K=D=1024, N=F=4096), then layer-1 GEMM (gelu, bf16 out)
  merge_transpose<8><<<16 * 64, 256, 0, stream>>>(W1, T_W1, coeff, Wb, 1024, 4096, 8);
  gemm_bt<2, true><<<dim3(4 * 32, 8), 256, 0, stream>>>(xb, Wb, b1b, hmid,
      512, 4096, 1024, (long)512 * 1024, (long)4096 * 1024, 4096, (long)512 * 4096);
  // 7. W2bT (K=F=4096, N=D=1024), then layer-2 GEMM (f32 out to d_out)
  merge_transpose<8><<<64 * 16, 256, 0, stream>>>(W2, T_W2, coeff, Wb, 4096, 1024, 8);
  gemm_bt<0, false><<<dim3(4 * 8, 8), 256, 0, stream>>>(hmid, Wb, b2b, out,
      512, 1024, 4096, (long)512 * 4096, (long)4096 * 1024, 1024, (long)512 * 1024);
}